// Round 15
// baseline (176.802 us; speedup 1.0000x reference)
//
#include <hip/hip_runtime.h>
#include <hip/hip_fp16.h>
#include <math.h>

#define DIM 128
#define BM 64
#define LDB 136   // u16 row stride for bf16 W tile in LDS (272B)
#define KVREC 384 // bytes per kv record: 128B fp8 k + 256B f16 v

typedef __attribute__((ext_vector_type(8))) short short8;
typedef __attribute__((ext_vector_type(4))) float f32x4;
typedef __attribute__((ext_vector_type(2))) float f32x2;
typedef unsigned short u16;
typedef unsigned int u32;
typedef unsigned char u8;

__device__ inline u16 f2bf(float f) {               // fp32 -> bf16 RNE
    union { float f; u32 u; } v; v.f = f;
    u32 r = v.u + 0x7fffu + ((v.u >> 16) & 1u);
    return (u16)(r >> 16);
}
__device__ inline u16 f2h(float f) {                // fp32 -> f16 RNE
    __half h = __float2half(f);
    union { __half h; u16 u; } v; v.h = h; return v.u;
}
__device__ inline float2 h2f2(u32 w) {              // packed f16 pair -> 2 fp32
    union { u32 u; __half2 h; } v; v.u = w;
    return __half22float2(v.h);
}

// fp8 decode: dword w -> 4 floats fused into an fma chain (2 elems per cvt)
#define DEC_FMA(w, q0, q1, q2, q3, d) {                          \
    f32x2 lo_ = __builtin_amdgcn_cvt_pk_f32_fp8((w), false);     \
    f32x2 hi_ = __builtin_amdgcn_cvt_pk_f32_fp8((w), true);      \
    d = fmaf(lo_.x, q0, d); d = fmaf(lo_.y, q1, d);              \
    d = fmaf(hi_.x, q2, d); d = fmaf(hi_.y, q3, d); }

// fp8 decode: dword w -> 4 floats
#define DEC4(w, o0, o1, o2, o3) {                                \
    f32x2 lo_ = __builtin_amdgcn_cvt_pk_f32_fp8((w), false);     \
    f32x2 hi_ = __builtin_amdgcn_cvt_pk_f32_fp8((w), true);      \
    o0 = lo_.x; o1 = lo_.y; o2 = hi_.x; o3 = hi_.y; }

// pack 8 floats -> 8 fp8 bytes (uint2)
#define PACK8(x0,x1,x2,x3,x4,x5,x6,x7, out) {                    \
    int d0_ = __builtin_amdgcn_cvt_pk_fp8_f32(x0, x1, 0, false); \
    d0_ = __builtin_amdgcn_cvt_pk_fp8_f32(x2, x3, d0_, true);    \
    int d1_ = __builtin_amdgcn_cvt_pk_fp8_f32(x4, x5, 0, false); \
    d1_ = __builtin_amdgcn_cvt_pk_fp8_f32(x6, x7, d1_, true);    \
    out.x = (u32)d0_; out.y = (u32)d1_; }

// f16 v accumulate: acc += p * f16pair (mad-mix folds cvt into fma_mix)
#define VACC2(w, p, a0, a1) { float2 f_ = h2f2(w);               \
    a0 = fmaf(p, f_.x, a0); a1 = fmaf(p, f_.y, a1); }

// Wkv[0..127] = fold(R, Wk); Wkv[128..255] = Wv. bkv likewise.
// NOTE: Wv CANNOT be folded past the aggregation (per-head attention weights
// -- R11); v must materialize at >=2 bytes (fp8 v's linear error fails -- R9).
__global__ void fold_relation_kv(const float* __restrict__ Wk, const float* __restrict__ bk,
                                 const float* __restrict__ Wv, const float* __restrict__ bv,
                                 const float* __restrict__ R, float* __restrict__ Wkv,
                                 float* __restrict__ bkv) {
    const int o = blockIdx.x;   // 0..255
    const int t = threadIdx.x;  // 0..127
    if (o < 128) {
        const int h = o >> 4, e = o & 15;
        float acc = 0.f;
#pragma unroll
        for (int d = 0; d < 16; ++d)
            acc = fmaf(R[h * 256 + d * 16 + e], Wk[(size_t)(h * 16 + d) * DIM + t], acc);
        Wkv[(size_t)o * DIM + t] = acc;
        if (t == 0) {
            float bb = 0.f;
#pragma unroll
            for (int d = 0; d < 16; ++d) bb = fmaf(R[h * 256 + d * 16 + e], bk[h * 16 + d], bb);
            bkv[o] = bb;
        }
    } else {
        Wkv[(size_t)o * DIM + t] = Wv[(size_t)(o - 128) * DIM + t];
        if (t == 0) bkv[o] = bv[o - 128];
    }
}

// Fused projections + seg_bounds. Blocks [0,gq): q (fp8 out). [gq,gq+gs):
// k fp8 + v f16 record. [gq+gs,...): seg_bounds.
__global__ __launch_bounds__(256, 4)
void proj_all(const float* __restrict__ fsrc, const float* __restrict__ fdst,
              const float* __restrict__ Wq, const float* __restrict__ bq,
              const float* __restrict__ Wkv, const float* __restrict__ bkv,
              const int* __restrict__ didx, int* __restrict__ seg, int E,
              u8* __restrict__ qo, u8* __restrict__ kvo,
              int n_dst, int n_src, int gq, int gs) {
    __shared__ __align__(16) u16 wl[DIM * LDB];
    const int bid = blockIdx.x;
    const int tid = threadIdx.x;

    if (bid >= gq + gs) {      // ---- seg_bounds blocks ----
        int e = (bid - gq - gs) * 256 + tid;
        if (e < E) {
            int d = didx[e];
            int dp = (e == 0) ? -1 : didx[e - 1];
            for (int x = dp + 1; x <= d; ++x) seg[x] = e;
            if (e == E - 1)
                for (int x = d + 1; x <= n_dst; ++x) seg[x] = E;
        }
        return;
    }

    const bool isQ = bid < gq;
    const int tile = isQ ? bid : bid - gq;
    const float* X = isQ ? fdst : fsrc;
    const int n = isQ ? n_dst : n_src;

    const int lane = tid & 63, wave = tid >> 6;
    const int lrow = lane & 15, kg = lane >> 4;
    const int rbase = tile * BM + wave * 16;
    int xr = rbase + lrow; if (xr > n - 1) xr = n - 1;
    const float* xp = X + (size_t)xr * DIM + kg * 8;

    short8 af[4];
#pragma unroll
    for (int kc = 0; kc < 4; ++kc) {
        float4 a0 = *(const float4*)(xp + kc * 32);
        float4 a1 = *(const float4*)(xp + kc * 32 + 4);
        short8 u;
        u[0] = (short)f2bf(a0.x); u[1] = (short)f2bf(a0.y);
        u[2] = (short)f2bf(a0.z); u[3] = (short)f2bf(a0.w);
        u[4] = (short)f2bf(a1.x); u[5] = (short)f2bf(a1.y);
        u[6] = (short)f2bf(a1.z); u[7] = (short)f2bf(a1.w);
        af[kc] = u;
    }

    const float* W0 = isQ ? Wq : Wkv;
#pragma unroll
    for (int it = 0; it < 8; ++it) {
        int flat = it * 256 + tid;
        int c = flat >> 4, ck = flat & 15;
        int slot = (c & 7) * 16 + (c >> 3);
        const float4* s = (const float4*)&W0[(size_t)c * DIM + ck * 8];
        float4 f0 = s[0], f1 = s[1];
        short8 u;
        u[0] = (short)f2bf(f0.x); u[1] = (short)f2bf(f0.y);
        u[2] = (short)f2bf(f0.z); u[3] = (short)f2bf(f0.w);
        u[4] = (short)f2bf(f1.x); u[5] = (short)f2bf(f1.y);
        u[6] = (short)f2bf(f1.z); u[7] = (short)f2bf(f1.w);
        *(short8*)&wl[slot * LDB + ck * 8] = u;
    }
    __syncthreads();

    f32x4 acck[8];
#pragma unroll
    for (int j = 0; j < 8; ++j) acck[j] = (f32x4){0.f, 0.f, 0.f, 0.f};
#pragma unroll
    for (int kc = 0; kc < 4; ++kc)
#pragma unroll
        for (int j = 0; j < 8; ++j) {
            short8 bf = *(const short8*)&wl[(j * 16 + lrow) * LDB + kc * 32 + kg * 8];
            acck[j] = __builtin_amdgcn_mfma_f32_16x16x32_bf16(af[kc], bf, acck[j], 0, 0, 0);
        }

    f32x4 accv[8];
    if (!isQ) {
        __syncthreads();
#pragma unroll
        for (int it = 0; it < 8; ++it) {
            int flat = it * 256 + tid;
            int c = flat >> 4, ck = flat & 15;
            int slot = (c & 7) * 16 + (c >> 3);
            const float4* s = (const float4*)&Wkv[(size_t)(128 + c) * DIM + ck * 8];
            float4 f0 = s[0], f1 = s[1];
            short8 u;
            u[0] = (short)f2bf(f0.x); u[1] = (short)f2bf(f0.y);
            u[2] = (short)f2bf(f0.z); u[3] = (short)f2bf(f0.w);
            u[4] = (short)f2bf(f1.x); u[5] = (short)f2bf(f1.y);
            u[6] = (short)f2bf(f1.z); u[7] = (short)f2bf(f1.w);
            *(short8*)&wl[slot * LDB + ck * 8] = u;
        }
        __syncthreads();
#pragma unroll
        for (int j = 0; j < 8; ++j) accv[j] = (f32x4){0.f, 0.f, 0.f, 0.f};
#pragma unroll
        for (int kc = 0; kc < 4; ++kc)
#pragma unroll
            for (int j = 0; j < 8; ++j) {
                short8 bf = *(const short8*)&wl[(j * 16 + lrow) * LDB + kc * 32 + kg * 8];
                accv[j] = __builtin_amdgcn_mfma_f32_16x16x32_bf16(af[kc], bf, accv[j], 0, 0, 0);
            }
    }

    if (isQ) {
        float bias[8];
        *(float4*)&bias[0] = *(const float4*)&bq[lrow * 8];
        *(float4*)&bias[4] = *(const float4*)&bq[lrow * 8 + 4];
#pragma unroll
        for (int r = 0; r < 4; ++r) {
            int gr = rbase + kg * 4 + r;
            if (gr < n) {
                uint2 qd;
                PACK8(acck[0][r] + bias[0], acck[1][r] + bias[1], acck[2][r] + bias[2],
                      acck[3][r] + bias[3], acck[4][r] + bias[4], acck[5][r] + bias[5],
                      acck[6][r] + bias[6], acck[7][r] + bias[7], qd);
                *(uint2*)&qo[(size_t)gr * 128 + lrow * 8] = qd;
            }
        }
    } else {
        float bk_[8], bv_[8];
        *(float4*)&bk_[0] = *(const float4*)&bkv[lrow * 8];
        *(float4*)&bk_[4] = *(const float4*)&bkv[lrow * 8 + 4];
        *(float4*)&bv_[0] = *(const float4*)&bkv[128 + lrow * 8];
        *(float4*)&bv_[4] = *(const float4*)&bkv[128 + lrow * 8 + 4];
#pragma unroll
        for (int r = 0; r < 4; ++r) {
            int gr = rbase + kg * 4 + r;
            if (gr < n) {
                uint2 kd;
                PACK8(acck[0][r] + bk_[0], acck[1][r] + bk_[1], acck[2][r] + bk_[2],
                      acck[3][r] + bk_[3], acck[4][r] + bk_[4], acck[5][r] + bk_[5],
                      acck[6][r] + bk_[6], acck[7][r] + bk_[7], kd);
                u16 o[8];
#pragma unroll
                for (int j = 0; j < 8; ++j) o[j] = f2h(accv[j][r] + bv_[j]);   // f16 v
                uint4 vd;
                vd.x = (u32)o[0] | ((u32)o[1] << 16);
                vd.y = (u32)o[2] | ((u32)o[3] << 16);
                vd.z = (u32)o[4] | ((u32)o[5] << 16);
                vd.w = (u32)o[6] | ((u32)o[7] << 16);
                u8* rec = kvo + (size_t)gr * KVREC;
                *(uint2*)(rec + lrow * 8) = kd;
                *(uint4*)(rec + 128 + lrow * 16) = vd;
            }
        }
    }
}

// ---- MFMA bf16 GEMM, bf16 X input, fp32 out (final projection) ----
__global__ __launch_bounds__(256, 4)
void gemm_mfma_b(const u16* __restrict__ X, const float* __restrict__ W,
                 const float* __restrict__ b, float* __restrict__ Y, int n) {
    __shared__ __align__(16) u16 wl[DIM * LDB];
    const int tid = threadIdx.x;
#pragma unroll
    for (int it = 0; it < 8; ++it) {
        int c8 = it * 256 + tid;
        int row = c8 >> 4, ck = c8 & 15;
        const float4* s = (const float4*)&W[(size_t)row * DIM + ck * 8];
        float4 f0 = s[0], f1 = s[1];
        short8 u;
        u[0] = (short)f2bf(f0.x); u[1] = (short)f2bf(f0.y);
        u[2] = (short)f2bf(f0.z); u[3] = (short)f2bf(f0.w);
        u[4] = (short)f2bf(f1.x); u[5] = (short)f2bf(f1.y);
        u[6] = (short)f2bf(f1.z); u[7] = (short)f2bf(f1.w);
        *(short8*)&wl[row * LDB + ck * 8] = u;
    }
    __syncthreads();
    const int lane = tid & 63, wave = tid >> 6;
    const int lrow = lane & 15, kg = lane >> 4;
    const int rbase = blockIdx.x * BM + wave * 16;
    int xr = rbase + lrow; if (xr > n - 1) xr = n - 1;
    const u16* xp = X + (size_t)xr * DIM + kg * 8;

    f32x4 acc[8];
#pragma unroll
    for (int j = 0; j < 8; ++j) acc[j] = (f32x4){0.f, 0.f, 0.f, 0.f};

#pragma unroll
    for (int kc = 0; kc < 4; ++kc) {
        short8 af = *(const short8*)(xp + kc * 32);
#pragma unroll
        for (int j = 0; j < 8; ++j) {
            short8 bf = *(const short8*)&wl[(j * 16 + lrow) * LDB + kc * 32 + kg * 8];
            acc[j] = __builtin_amdgcn_mfma_f32_16x16x32_bf16(af, bf, acc[j], 0, 0, 0);
        }
    }
#pragma unroll
    for (int r = 0; r < 4; ++r) {
        int gr = rbase + kg * 4 + r;
        if (gr < n) {
#pragma unroll
            for (int j = 0; j < 8; ++j) {
                int c = j * 16 + lrow;
                Y[(size_t)gr * DIM + c] = acc[j][r] + b[c];
            }
        }
    }
}

// ONE WAVE per dst, 4 dst per block. Thread = (edge slot g=lane>>3, head
// h=lane&7). q fp8 (16B/head), 384B kv records: k fp8 (16B/head-lane),
// v f16 (32B/head-lane, fma_mix accumulate). 4-way split k-dot for ILP.
__global__ __launch_bounds__(256, 8)
void edge_attn11(const u8* __restrict__ q, const u8* __restrict__ kv,
                 const int* __restrict__ sidx, const int* __restrict__ seg,
                 u16* __restrict__ hout, int n_dst) {
    const int wave = threadIdx.x >> 6;
    const int lane = threadIdx.x & 63;
    const int dst = blockIdx.x * 4 + wave;
    if (dst >= n_dst) return;
    const int g = lane >> 3, h = lane & 7;

    const int s0 = seg[dst], s1 = seg[dst + 1];

    uint4 qa = *(const uint4*)(q + (size_t)dst * 128 + h * 16);
    float qf[16];
    DEC4(qa.x, qf[0],  qf[1],  qf[2],  qf[3]);
    DEC4(qa.y, qf[4],  qf[5],  qf[6],  qf[7]);
    DEC4(qa.z, qf[8],  qf[9],  qf[10], qf[11]);
    DEC4(qa.w, qf[12], qf[13], qf[14], qf[15]);

    float ssum = 0.f;
    float acc[16];
#pragma unroll
    for (int j = 0; j < 16; ++j) acc[j] = 0.f;

#pragma unroll 2
    for (int e = s0 + g; e < s1; e += 8) {
        const int row = sidx[e];
        const u8* rec = kv + (size_t)row * KVREC;
        uint4 k4 = *(const uint4*)(rec + h * 16);
        uint4 v0 = *(const uint4*)(rec + 128 + h * 32);
        uint4 v1 = *(const uint4*)(rec + 128 + h * 32 + 16);
        float d0 = 0.f, d1 = 0.f, d2 = 0.f, d3 = 0.f;   // 4-way ILP split
        DEC_FMA(k4.x, qf[0],  qf[1],  qf[2],  qf[3],  d0);
        DEC_FMA(k4.y, qf[4],  qf[5],  qf[6],  qf[7],  d1);
        DEC_FMA(k4.z, qf[8],  qf[9],  qf[10], qf[11], d2);
        DEC_FMA(k4.w, qf[12], qf[13], qf[14], qf[15], d3);
        float d = (d0 + d1) + (d2 + d3);
        float lg = d * 0.25f;
        lg = (lg >= 0.f) ? lg : 0.2f * lg;
        const float p = __expf(lg);
        ssum += p;
        VACC2(v0.x, p, acc[0],  acc[1]);
        VACC2(v0.y, p, acc[2],  acc[3]);
        VACC2(v0.z, p, acc[4],  acc[5]);
        VACC2(v0.w, p, acc[6],  acc[7]);
        VACC2(v1.x, p, acc[8],  acc[9]);
        VACC2(v1.y, p, acc[10], acc[11]);
        VACC2(v1.z, p, acc[12], acc[13]);
        VACC2(v1.w, p, acc[14], acc[15]);
    }

#pragma unroll
    for (int j = 0; j < 16; ++j) {
        acc[j] += __shfl_xor(acc[j], 8);
        acc[j] += __shfl_xor(acc[j], 16);
        acc[j] += __shfl_xor(acc[j], 32);
    }
    ssum += __shfl_xor(ssum, 8);
    ssum += __shfl_xor(ssum, 16);
    ssum += __shfl_xor(ssum, 32);

    if (g == 0) {
        const float inv = (ssum > 0.f) ? 1.f / ssum : 0.f;
        u16 o[16];
#pragma unroll
        for (int j = 0; j < 16; ++j) o[j] = f2bf(acc[j] * inv);
        uint4 pa, pb;
        pa.x = (u32)o[0]  | ((u32)o[1]  << 16);
        pa.y = (u32)o[2]  | ((u32)o[3]  << 16);
        pa.z = (u32)o[4]  | ((u32)o[5]  << 16);
        pa.w = (u32)o[6]  | ((u32)o[7]  << 16);
        pb.x = (u32)o[8]  | ((u32)o[9]  << 16);
        pb.y = (u32)o[10] | ((u32)o[11] << 16);
        pb.z = (u32)o[12] | ((u32)o[13] << 16);
        pb.w = (u32)o[14] | ((u32)o[15] << 16);
        ((uint4*)hout)[(size_t)dst * 16 + h * 2]     = pa;
        ((uint4*)hout)[(size_t)dst * 16 + h * 2 + 1] = pb;
    }
}

extern "C" void kernel_launch(void* const* d_in, const int* in_sizes, int n_in,
                              void* d_out, int out_size, void* d_ws, size_t ws_size,
                              hipStream_t stream) {
    const float* feat_src = (const float*)d_in[0];
    const float* feat_dst = (const float*)d_in[1];
    const int*   src_idx  = (const int*)d_in[2];
    const int*   dst_idx  = (const int*)d_in[3];
    const float* Wq = (const float*)d_in[4];
    const float* bq = (const float*)d_in[5];
    const float* Wk = (const float*)d_in[6];
    const float* bk = (const float*)d_in[7];
    const float* Wv = (const float*)d_in[8];
    const float* bv = (const float*)d_in[9];
    const float* R  = (const float*)d_in[10];
    const float* Wo = (const float*)d_in[11];
    const float* bo = (const float*)d_in[12];

    const int n_src = in_sizes[0] / DIM;
    const int n_dst = in_sizes[1] / DIM;
    const int E     = in_sizes[2];

    float* out = (float*)d_out;
    u8*  q   = (u8*)d_ws;                               // n_dst x 128 fp8
    u8*  kv  = q + (size_t)n_dst * 128;                 // n_src x 384B (k fp8 | v f16)
    u16* hag = (u16*)(kv + (size_t)n_src * KVREC);      // n_dst x 128 bf16
    int* seg = (int*)(hag + (size_t)n_dst * DIM);       // n_dst+1 ints
    size_t segEnd = ((size_t)(n_dst + 1) + 3) & ~(size_t)3;
    float* Wkv = (float*)(seg + segEnd);                // 256x128 fp32
    float* bkv = Wkv + 256 * DIM;                       // 256 fp32

    const int gq = (n_dst + BM - 1) / BM;
    const int gs = (n_src + BM - 1) / BM;
    const int gE = (E + 255) / 256;

    fold_relation_kv<<<256, DIM, 0, stream>>>(Wk, bk, Wv, bv, R, Wkv, bkv);
    proj_all<<<gq + gs + gE, 256, 0, stream>>>(feat_src, feat_dst, Wq, bq, Wkv, bkv,
                                               dst_idx, seg, E, q, kv, n_dst, n_src, gq, gs);
    edge_attn11<<<(n_dst + 3) / 4, 256, 0, stream>>>(q, kv, src_idx, seg, hag, n_dst);
    gemm_mfma_b<<<gq, 256, 0, stream>>>(hag, Wo, bo, out, n_dst);
}

// Round 16
// 86.575 us; speedup vs baseline: 2.0422x; 2.0422x over previous
//
#include <hip/hip_runtime.h>
#include <math.h>

#define DIM 128
#define BM 64
#define LDB 136   // u16 row stride for bf16 W tile in LDS (272B)
#define KVREC 384 // bytes per kv record: 128B fp8 k + 256B bf16 v

typedef __attribute__((ext_vector_type(8))) short short8;
typedef __attribute__((ext_vector_type(4))) float f32x4;
typedef __attribute__((ext_vector_type(2))) float f32x2;
typedef unsigned short u16;
typedef unsigned int u32;
typedef unsigned char u8;

__device__ inline u16 f2bf(float f) {               // fp32 -> bf16 RNE
    union { float f; u32 u; } v; v.f = f;
    u32 r = v.u + 0x7fffu + ((v.u >> 16) & 1u);
    return (u16)(r >> 16);
}
__device__ inline float bfl(u32 u) { union { u32 u; float f; } v; v.u = u << 16; return v.f; }
__device__ inline float bfh(u32 u) { union { u32 u; float f; } v; v.u = u & 0xffff0000u; return v.f; }

// fp8 decode: dword w -> 4 floats fused into an fma chain (2 elems per cvt)
#define DEC_FMA(w, q0, q1, q2, q3, d) {                          \
    f32x2 lo_ = __builtin_amdgcn_cvt_pk_f32_fp8((w), false);     \
    f32x2 hi_ = __builtin_amdgcn_cvt_pk_f32_fp8((w), true);      \
    d = fmaf(lo_.x, q0, d); d = fmaf(lo_.y, q1, d);              \
    d = fmaf(hi_.x, q2, d); d = fmaf(hi_.y, q3, d); }

// fp8 decode: dword w -> 4 floats
#define DEC4(w, o0, o1, o2, o3) {                                \
    f32x2 lo_ = __builtin_amdgcn_cvt_pk_f32_fp8((w), false);     \
    f32x2 hi_ = __builtin_amdgcn_cvt_pk_f32_fp8((w), true);      \
    o0 = lo_.x; o1 = lo_.y; o2 = hi_.x; o3 = hi_.y; }

// pack 8 floats -> 8 fp8 bytes (uint2)
#define PACK8(x0,x1,x2,x3,x4,x5,x6,x7, out) {                    \
    int d0_ = __builtin_amdgcn_cvt_pk_fp8_f32(x0, x1, 0, false); \
    d0_ = __builtin_amdgcn_cvt_pk_fp8_f32(x2, x3, d0_, true);    \
    int d1_ = __builtin_amdgcn_cvt_pk_fp8_f32(x4, x5, 0, false); \
    d1_ = __builtin_amdgcn_cvt_pk_fp8_f32(x6, x7, d1_, true);    \
    out.x = (u32)d0_; out.y = (u32)d1_; }

// Wkv[0..127] = fold(R, Wk); Wkv[128..255] = Wv. bkv likewise.
// NOTE: Wv CANNOT be folded past the aggregation (per-head attention weights
// -- R11); v must materialize at >=2B (fp8 v's linear error fails -- R9);
// v decode must stay bit-ops (f16 cvt path spills at the occupancy cap -- R14).
__global__ void fold_relation_kv(const float* __restrict__ Wk, const float* __restrict__ bk,
                                 const float* __restrict__ Wv, const float* __restrict__ bv,
                                 const float* __restrict__ R, float* __restrict__ Wkv,
                                 float* __restrict__ bkv) {
    const int o = blockIdx.x;   // 0..255
    const int t = threadIdx.x;  // 0..127
    if (o < 128) {
        const int h = o >> 4, e = o & 15;
        float acc = 0.f;
#pragma unroll
        for (int d = 0; d < 16; ++d)
            acc = fmaf(R[h * 256 + d * 16 + e], Wk[(size_t)(h * 16 + d) * DIM + t], acc);
        Wkv[(size_t)o * DIM + t] = acc;
        if (t == 0) {
            float bb = 0.f;
#pragma unroll
            for (int d = 0; d < 16; ++d) bb = fmaf(R[h * 256 + d * 16 + e], bk[h * 16 + d], bb);
            bkv[o] = bb;
        }
    } else {
        Wkv[(size_t)o * DIM + t] = Wv[(size_t)(o - 128) * DIM + t];
        if (t == 0) bkv[o] = bv[o - 128];
    }
}

// Fused projections + seg_bounds. Blocks [0,gq): q (fp8 out). [gq,gq+gs):
// k fp8 + v bf16 record. [gq+gs,...): seg_bounds.
__global__ __launch_bounds__(256, 4)
void proj_all(const float* __restrict__ fsrc, const float* __restrict__ fdst,
              const float* __restrict__ Wq, const float* __restrict__ bq,
              const float* __restrict__ Wkv, const float* __restrict__ bkv,
              const int* __restrict__ didx, int* __restrict__ seg, int E,
              u8* __restrict__ qo, u8* __restrict__ kvo,
              int n_dst, int n_src, int gq, int gs) {
    __shared__ __align__(16) u16 wl[DIM * LDB];
    const int bid = blockIdx.x;
    const int tid = threadIdx.x;

    if (bid >= gq + gs) {      // ---- seg_bounds blocks ----
        int e = (bid - gq - gs) * 256 + tid;
        if (e < E) {
            int d = didx[e];
            int dp = (e == 0) ? -1 : didx[e - 1];
            for (int x = dp + 1; x <= d; ++x) seg[x] = e;
            if (e == E - 1)
                for (int x = d + 1; x <= n_dst; ++x) seg[x] = E;
        }
        return;
    }

    const bool isQ = bid < gq;
    const int tile = isQ ? bid : bid - gq;
    const float* X = isQ ? fdst : fsrc;
    const int n = isQ ? n_dst : n_src;

    const int lane = tid & 63, wave = tid >> 6;
    const int lrow = lane & 15, kg = lane >> 4;
    const int rbase = tile * BM + wave * 16;
    int xr = rbase + lrow; if (xr > n - 1) xr = n - 1;
    const float* xp = X + (size_t)xr * DIM + kg * 8;

    short8 af[4];
#pragma unroll
    for (int kc = 0; kc < 4; ++kc) {
        float4 a0 = *(const float4*)(xp + kc * 32);
        float4 a1 = *(const float4*)(xp + kc * 32 + 4);
        short8 u;
        u[0] = (short)f2bf(a0.x); u[1] = (short)f2bf(a0.y);
        u[2] = (short)f2bf(a0.z); u[3] = (short)f2bf(a0.w);
        u[4] = (short)f2bf(a1.x); u[5] = (short)f2bf(a1.y);
        u[6] = (short)f2bf(a1.z); u[7] = (short)f2bf(a1.w);
        af[kc] = u;
    }

    const float* W0 = isQ ? Wq : Wkv;
#pragma unroll
    for (int it = 0; it < 8; ++it) {
        int flat = it * 256 + tid;
        int c = flat >> 4, ck = flat & 15;
        int slot = (c & 7) * 16 + (c >> 3);
        const float4* s = (const float4*)&W0[(size_t)c * DIM + ck * 8];
        float4 f0 = s[0], f1 = s[1];
        short8 u;
        u[0] = (short)f2bf(f0.x); u[1] = (short)f2bf(f0.y);
        u[2] = (short)f2bf(f0.z); u[3] = (short)f2bf(f0.w);
        u[4] = (short)f2bf(f1.x); u[5] = (short)f2bf(f1.y);
        u[6] = (short)f2bf(f1.z); u[7] = (short)f2bf(f1.w);
        *(short8*)&wl[slot * LDB + ck * 8] = u;
    }
    __syncthreads();

    f32x4 acck[8];
#pragma unroll
    for (int j = 0; j < 8; ++j) acck[j] = (f32x4){0.f, 0.f, 0.f, 0.f};
#pragma unroll
    for (int kc = 0; kc < 4; ++kc)
#pragma unroll
        for (int j = 0; j < 8; ++j) {
            short8 bf = *(const short8*)&wl[(j * 16 + lrow) * LDB + kc * 32 + kg * 8];
            acck[j] = __builtin_amdgcn_mfma_f32_16x16x32_bf16(af[kc], bf, acck[j], 0, 0, 0);
        }

    f32x4 accv[8];
    if (!isQ) {
        __syncthreads();
#pragma unroll
        for (int it = 0; it < 8; ++it) {
            int flat = it * 256 + tid;
            int c = flat >> 4, ck = flat & 15;
            int slot = (c & 7) * 16 + (c >> 3);
            const float4* s = (const float4*)&Wkv[(size_t)(128 + c) * DIM + ck * 8];
            float4 f0 = s[0], f1 = s[1];
            short8 u;
            u[0] = (short)f2bf(f0.x); u[1] = (short)f2bf(f0.y);
            u[2] = (short)f2bf(f0.z); u[3] = (short)f2bf(f0.w);
            u[4] = (short)f2bf(f1.x); u[5] = (short)f2bf(f1.y);
            u[6] = (short)f2bf(f1.z); u[7] = (short)f2bf(f1.w);
            *(short8*)&wl[slot * LDB + ck * 8] = u;
        }
        __syncthreads();
#pragma unroll
        for (int j = 0; j < 8; ++j) accv[j] = (f32x4){0.f, 0.f, 0.f, 0.f};
#pragma unroll
        for (int kc = 0; kc < 4; ++kc)
#pragma unroll
            for (int j = 0; j < 8; ++j) {
                short8 bf = *(const short8*)&wl[(j * 16 + lrow) * LDB + kc * 32 + kg * 8];
                accv[j] = __builtin_amdgcn_mfma_f32_16x16x32_bf16(af[kc], bf, accv[j], 0, 0, 0);
            }
    }

    if (isQ) {
        float bias[8];
        *(float4*)&bias[0] = *(const float4*)&bq[lrow * 8];
        *(float4*)&bias[4] = *(const float4*)&bq[lrow * 8 + 4];
#pragma unroll
        for (int r = 0; r < 4; ++r) {
            int gr = rbase + kg * 4 + r;
            if (gr < n) {
                uint2 qd;
                PACK8(acck[0][r] + bias[0], acck[1][r] + bias[1], acck[2][r] + bias[2],
                      acck[3][r] + bias[3], acck[4][r] + bias[4], acck[5][r] + bias[5],
                      acck[6][r] + bias[6], acck[7][r] + bias[7], qd);
                *(uint2*)&qo[(size_t)gr * 128 + lrow * 8] = qd;
            }
        }
    } else {
        float bk_[8], bv_[8];
        *(float4*)&bk_[0] = *(const float4*)&bkv[lrow * 8];
        *(float4*)&bk_[4] = *(const float4*)&bkv[lrow * 8 + 4];
        *(float4*)&bv_[0] = *(const float4*)&bkv[128 + lrow * 8];
        *(float4*)&bv_[4] = *(const float4*)&bkv[128 + lrow * 8 + 4];
#pragma unroll
        for (int r = 0; r < 4; ++r) {
            int gr = rbase + kg * 4 + r;
            if (gr < n) {
                uint2 kd;
                PACK8(acck[0][r] + bk_[0], acck[1][r] + bk_[1], acck[2][r] + bk_[2],
                      acck[3][r] + bk_[3], acck[4][r] + bk_[4], acck[5][r] + bk_[5],
                      acck[6][r] + bk_[6], acck[7][r] + bk_[7], kd);
                u16 o[8];
#pragma unroll
                for (int j = 0; j < 8; ++j) o[j] = f2bf(accv[j][r] + bv_[j]);
                uint4 vd;
                vd.x = (u32)o[0] | ((u32)o[1] << 16);
                vd.y = (u32)o[2] | ((u32)o[3] << 16);
                vd.z = (u32)o[4] | ((u32)o[5] << 16);
                vd.w = (u32)o[6] | ((u32)o[7] << 16);
                u8* rec = kvo + (size_t)gr * KVREC;
                *(uint2*)(rec + lrow * 8) = kd;
                *(uint4*)(rec + 128 + lrow * 16) = vd;
            }
        }
    }
}

// ---- MFMA bf16 GEMM, bf16 X input, fp32 out (final projection) ----
__global__ __launch_bounds__(256, 4)
void gemm_mfma_b(const u16* __restrict__ X, const float* __restrict__ W,
                 const float* __restrict__ b, float* __restrict__ Y, int n) {
    __shared__ __align__(16) u16 wl[DIM * LDB];
    const int tid = threadIdx.x;
#pragma unroll
    for (int it = 0; it < 8; ++it) {
        int c8 = it * 256 + tid;
        int row = c8 >> 4, ck = c8 & 15;
        const float4* s = (const float4*)&W[(size_t)row * DIM + ck * 8];
        float4 f0 = s[0], f1 = s[1];
        short8 u;
        u[0] = (short)f2bf(f0.x); u[1] = (short)f2bf(f0.y);
        u[2] = (short)f2bf(f0.z); u[3] = (short)f2bf(f0.w);
        u[4] = (short)f2bf(f1.x); u[5] = (short)f2bf(f1.y);
        u[6] = (short)f2bf(f1.z); u[7] = (short)f2bf(f1.w);
        *(short8*)&wl[row * LDB + ck * 8] = u;
    }
    __syncthreads();
    const int lane = tid & 63, wave = tid >> 6;
    const int lrow = lane & 15, kg = lane >> 4;
    const int rbase = blockIdx.x * BM + wave * 16;
    int xr = rbase + lrow; if (xr > n - 1) xr = n - 1;
    const u16* xp = X + (size_t)xr * DIM + kg * 8;

    f32x4 acc[8];
#pragma unroll
    for (int j = 0; j < 8; ++j) acc[j] = (f32x4){0.f, 0.f, 0.f, 0.f};

#pragma unroll
    for (int kc = 0; kc < 4; ++kc) {
        short8 af = *(const short8*)(xp + kc * 32);
#pragma unroll
        for (int j = 0; j < 8; ++j) {
            short8 bf = *(const short8*)&wl[(j * 16 + lrow) * LDB + kc * 32 + kg * 8];
            acc[j] = __builtin_amdgcn_mfma_f32_16x16x32_bf16(af, bf, acc[j], 0, 0, 0);
        }
    }
#pragma unroll
    for (int r = 0; r < 4; ++r) {
        int gr = rbase + kg * 4 + r;
        if (gr < n) {
#pragma unroll
            for (int j = 0; j < 8; ++j) {
                int c = j * 16 + lrow;
                Y[(size_t)gr * DIM + c] = acc[j][r] + b[c];
            }
        }
    }
}

// ONE WAVE per dst, 4 dst per block. Thread = (edge slot g=lane>>3, head
// h=lane&7). q fp8 (16B/head), 384B kv records: k fp8 (16B/head-lane),
// v bf16 (32B/head-lane, bit-op unpack). No LDS, no barriers in loop.
__global__ __launch_bounds__(256, 8)
void edge_attn10(const u8* __restrict__ q, const u8* __restrict__ kv,
                 const int* __restrict__ sidx, const int* __restrict__ seg,
                 u16* __restrict__ hout, int n_dst) {
    const int wave = threadIdx.x >> 6;
    const int lane = threadIdx.x & 63;
    const int dst = blockIdx.x * 4 + wave;
    if (dst >= n_dst) return;
    const int g = lane >> 3, h = lane & 7;

    const int s0 = seg[dst], s1 = seg[dst + 1];

    // this head's 16 q values (16B fp8 -> 16 fp32 via 8 cvt_pk)
    uint4 qa = *(const uint4*)(q + (size_t)dst * 128 + h * 16);
    float qf[16];
    DEC4(qa.x, qf[0],  qf[1],  qf[2],  qf[3]);
    DEC4(qa.y, qf[4],  qf[5],  qf[6],  qf[7]);
    DEC4(qa.z, qf[8],  qf[9],  qf[10], qf[11]);
    DEC4(qa.w, qf[12], qf[13], qf[14], qf[15]);

    float ssum = 0.f;
    float acc[16];
#pragma unroll
    for (int j = 0; j < 16; ++j) acc[j] = 0.f;

#pragma unroll 2
    for (int e = s0 + g; e < s1; e += 8) {
        const int row = sidx[e];
        const u8* rec = kv + (size_t)row * KVREC;
        uint4 k4 = *(const uint4*)(rec + h * 16);
        uint4 v0 = *(const uint4*)(rec + 128 + h * 32);
        uint4 v1 = *(const uint4*)(rec + 128 + h * 32 + 16);
        float d = 0.f;
        DEC_FMA(k4.x, qf[0],  qf[1],  qf[2],  qf[3],  d);
        DEC_FMA(k4.y, qf[4],  qf[5],  qf[6],  qf[7],  d);
        DEC_FMA(k4.z, qf[8],  qf[9],  qf[10], qf[11], d);
        DEC_FMA(k4.w, qf[12], qf[13], qf[14], qf[15], d);
        float lg = d * 0.25f;
        lg = (lg >= 0.f) ? lg : 0.2f * lg;
        const float p = __expf(lg);
        ssum += p;
        acc[0]  = fmaf(p, bfl(v0.x), acc[0]);  acc[1]  = fmaf(p, bfh(v0.x), acc[1]);
        acc[2]  = fmaf(p, bfl(v0.y), acc[2]);  acc[3]  = fmaf(p, bfh(v0.y), acc[3]);
        acc[4]  = fmaf(p, bfl(v0.z), acc[4]);  acc[5]  = fmaf(p, bfh(v0.z), acc[5]);
        acc[6]  = fmaf(p, bfl(v0.w), acc[6]);  acc[7]  = fmaf(p, bfh(v0.w), acc[7]);
        acc[8]  = fmaf(p, bfl(v1.x), acc[8]);  acc[9]  = fmaf(p, bfh(v1.x), acc[9]);
        acc[10] = fmaf(p, bfl(v1.y), acc[10]); acc[11] = fmaf(p, bfh(v1.y), acc[11]);
        acc[12] = fmaf(p, bfl(v1.z), acc[12]); acc[13] = fmaf(p, bfh(v1.z), acc[13]);
        acc[14] = fmaf(p, bfl(v1.w), acc[14]); acc[15] = fmaf(p, bfh(v1.w), acc[15]);
    }

#pragma unroll
    for (int j = 0; j < 16; ++j) {
        acc[j] += __shfl_xor(acc[j], 8);
        acc[j] += __shfl_xor(acc[j], 16);
        acc[j] += __shfl_xor(acc[j], 32);
    }
    ssum += __shfl_xor(ssum, 8);
    ssum += __shfl_xor(ssum, 16);
    ssum += __shfl_xor(ssum, 32);

    if (g == 0) {
        const float inv = (ssum > 0.f) ? 1.f / ssum : 0.f;
        u16 o[16];
#pragma unroll
        for (int j = 0; j < 16; ++j) o[j] = f2bf(acc[j] * inv);
        uint4 pa, pb;
        pa.x = (u32)o[0]  | ((u32)o[1]  << 16);
        pa.y = (u32)o[2]  | ((u32)o[3]  << 16);
        pa.z = (u32)o[4]  | ((u32)o[5]  << 16);
        pa.w = (u32)o[6]  | ((u32)o[7]  << 16);
        pb.x = (u32)o[8]  | ((u32)o[9]  << 16);
        pb.y = (u32)o[10] | ((u32)o[11] << 16);
        pb.z = (u32)o[12] | ((u32)o[13] << 16);
        pb.w = (u32)o[14] | ((u32)o[15] << 16);
        ((uint4*)hout)[(size_t)dst * 16 + h * 2]     = pa;
        ((uint4*)hout)[(size_t)dst * 16 + h * 2 + 1] = pb;
    }
}

extern "C" void kernel_launch(void* const* d_in, const int* in_sizes, int n_in,
                              void* d_out, int out_size, void* d_ws, size_t ws_size,
                              hipStream_t stream) {
    const float* feat_src = (const float*)d_in[0];
    const float* feat_dst = (const float*)d_in[1];
    const int*   src_idx  = (const int*)d_in[2];
    const int*   dst_idx  = (const int*)d_in[3];
    const float* Wq = (const float*)d_in[4];
    const float* bq = (const float*)d_in[5];
    const float* Wk = (const float*)d_in[6];
    const float* bk = (const float*)d_in[7];
    const float* Wv = (const float*)d_in[8];
    const float* bv = (const float*)d_in[9];
    const float* R  = (const float*)d_in[10];
    const float* Wo = (const float*)d_in[11];
    const float* bo = (const float*)d_in[12];

    const int n_src = in_sizes[0] / DIM;
    const int n_dst = in_sizes[1] / DIM;
    const int E     = in_sizes[2];

    float* out = (float*)d_out;
    u8*  q   = (u8*)d_ws;                               // n_dst x 128 fp8
    u8*  kv  = q + (size_t)n_dst * 128;                 // n_src x 384B (k fp8 | v bf16)
    u16* hag = (u16*)(kv + (size_t)n_src * KVREC);      // n_dst x 128 bf16
    int* seg = (int*)(hag + (size_t)n_dst * DIM);       // n_dst+1 ints
    size_t segEnd = ((size_t)(n_dst + 1) + 3) & ~(size_t)3;
    float* Wkv = (float*)(seg + segEnd);                // 256x128 fp32
    float* bkv = Wkv + 256 * DIM;                       // 256 fp32

    const int gq = (n_dst + BM - 1) / BM;
    const int gs = (n_src + BM - 1) / BM;
    const int gE = (E + 255) / 256;

    fold_relation_kv<<<256, DIM, 0, stream>>>(Wk, bk, Wv, bv, R, Wkv, bkv);
    proj_all<<<gq + gs + gE, 256, 0, stream>>>(feat_src, feat_dst, Wq, bq, Wkv, bkv,
                                               dst_idx, seg, E, q, kv, n_dst, n_src, gq, gs);
    edge_attn10<<<(n_dst + 3) / 4, 256, 0, stream>>>(q, kv, src_idx, seg, hag, n_dst);
    gemm_mfma_b<<<gq, 256, 0, stream>>>(hag, Wo, bo, out, n_dst);
}

// Round 17
// 83.876 us; speedup vs baseline: 2.1079x; 1.0322x over previous
//
#include <hip/hip_runtime.h>
#include <hip/hip_fp16.h>
#include <math.h>

#define DIM 128
#define BM 64
#define LDB 136   // u16 row stride for bf16 W tile in LDS (272B)
#define KVREC 384 // bytes per kv record: 128B fp8 k + 256B f16 v

typedef __attribute__((ext_vector_type(8))) short short8;
typedef __attribute__((ext_vector_type(4))) float f32x4;
typedef __attribute__((ext_vector_type(2))) float f32x2;
typedef unsigned short u16;
typedef unsigned int u32;
typedef unsigned char u8;

__device__ inline u16 f2bf(float f) {               // fp32 -> bf16 RNE
    union { float f; u32 u; } v; v.f = f;
    u32 r = v.u + 0x7fffu + ((v.u >> 16) & 1u);
    return (u16)(r >> 16);
}
__device__ inline u16 f2h(float f) {                // fp32 -> f16 RNE
    union { __half h; u16 u; } v; v.h = __float2half(f); return v.u;
}

// fp8 decode: dword w -> 4 floats fused into an fma chain (2 elems per cvt)
#define DEC_FMA(w, q0, q1, q2, q3, d) {                          \
    f32x2 lo_ = __builtin_amdgcn_cvt_pk_f32_fp8((w), false);     \
    f32x2 hi_ = __builtin_amdgcn_cvt_pk_f32_fp8((w), true);      \
    d = fmaf(lo_.x, q0, d); d = fmaf(lo_.y, q1, d);              \
    d = fmaf(hi_.x, q2, d); d = fmaf(hi_.y, q3, d); }

// fp8 decode: dword w -> 4 floats
#define DEC4(w, o0, o1, o2, o3) {                                \
    f32x2 lo_ = __builtin_amdgcn_cvt_pk_f32_fp8((w), false);     \
    f32x2 hi_ = __builtin_amdgcn_cvt_pk_f32_fp8((w), true);      \
    o0 = lo_.x; o1 = lo_.y; o2 = hi_.x; o3 = hi_.y; }

// pack 8 floats -> 8 fp8 bytes (uint2)
#define PACK8(x0,x1,x2,x3,x4,x5,x6,x7, out) {                    \
    int d0_ = __builtin_amdgcn_cvt_pk_fp8_f32(x0, x1, 0, false); \
    d0_ = __builtin_amdgcn_cvt_pk_fp8_f32(x2, x3, d0_, true);    \
    int d1_ = __builtin_amdgcn_cvt_pk_fp8_f32(x4, x5, 0, false); \
    d1_ = __builtin_amdgcn_cvt_pk_fp8_f32(x6, x7, d1_, true);    \
    out.x = (u32)d0_; out.y = (u32)d1_; }

// packed f16 accumulate: a (half2) += p2 * bitcast<half2>(w)  -- v_pk_fma_f16
#define HACC(w, p2, a) { union { u32 u; __half2 h; } c_; c_.u = (w); \
    a = __hfma2((p2), c_.h, (a)); }

// Wkv[0..127] = fold(R, Wk); Wkv[128..255] = Wv. bkv likewise.
// NOTE: Wv CANNOT be folded past the aggregation (per-head attention weights
// -- R11); v must materialize at >=2B (fp8 v's linear error fails -- R9);
// per-edge f32 unpack temporaries spill at the occupancy cap (R14) -- v is
// consumed PACKED via v_pk_fma_f16, unpacked only once per dst.
__global__ void fold_relation_kv(const float* __restrict__ Wk, const float* __restrict__ bk,
                                 const float* __restrict__ Wv, const float* __restrict__ bv,
                                 const float* __restrict__ R, float* __restrict__ Wkv,
                                 float* __restrict__ bkv) {
    const int o = blockIdx.x;   // 0..255
    const int t = threadIdx.x;  // 0..127
    if (o < 128) {
        const int h = o >> 4, e = o & 15;
        float acc = 0.f;
#pragma unroll
        for (int d = 0; d < 16; ++d)
            acc = fmaf(R[h * 256 + d * 16 + e], Wk[(size_t)(h * 16 + d) * DIM + t], acc);
        Wkv[(size_t)o * DIM + t] = acc;
        if (t == 0) {
            float bb = 0.f;
#pragma unroll
            for (int d = 0; d < 16; ++d) bb = fmaf(R[h * 256 + d * 16 + e], bk[h * 16 + d], bb);
            bkv[o] = bb;
        }
    } else {
        Wkv[(size_t)o * DIM + t] = Wv[(size_t)(o - 128) * DIM + t];
        if (t == 0) bkv[o] = bv[o - 128];
    }
}

// Fused projections + seg_bounds. Blocks [0,gq): q (fp8 out). [gq,gq+gs):
// k fp8 + v f16 record. [gq+gs,...): seg_bounds.
__global__ __launch_bounds__(256, 4)
void proj_all(const float* __restrict__ fsrc, const float* __restrict__ fdst,
              const float* __restrict__ Wq, const float* __restrict__ bq,
              const float* __restrict__ Wkv, const float* __restrict__ bkv,
              const int* __restrict__ didx, int* __restrict__ seg, int E,
              u8* __restrict__ qo, u8* __restrict__ kvo,
              int n_dst, int n_src, int gq, int gs) {
    __shared__ __align__(16) u16 wl[DIM * LDB];
    const int bid = blockIdx.x;
    const int tid = threadIdx.x;

    if (bid >= gq + gs) {      // ---- seg_bounds blocks ----
        int e = (bid - gq - gs) * 256 + tid;
        if (e < E) {
            int d = didx[e];
            int dp = (e == 0) ? -1 : didx[e - 1];
            for (int x = dp + 1; x <= d; ++x) seg[x] = e;
            if (e == E - 1)
                for (int x = d + 1; x <= n_dst; ++x) seg[x] = E;
        }
        return;
    }

    const bool isQ = bid < gq;
    const int tile = isQ ? bid : bid - gq;
    const float* X = isQ ? fdst : fsrc;
    const int n = isQ ? n_dst : n_src;

    const int lane = tid & 63, wave = tid >> 6;
    const int lrow = lane & 15, kg = lane >> 4;
    const int rbase = tile * BM + wave * 16;
    int xr = rbase + lrow; if (xr > n - 1) xr = n - 1;
    const float* xp = X + (size_t)xr * DIM + kg * 8;

    short8 af[4];
#pragma unroll
    for (int kc = 0; kc < 4; ++kc) {
        float4 a0 = *(const float4*)(xp + kc * 32);
        float4 a1 = *(const float4*)(xp + kc * 32 + 4);
        short8 u;
        u[0] = (short)f2bf(a0.x); u[1] = (short)f2bf(a0.y);
        u[2] = (short)f2bf(a0.z); u[3] = (short)f2bf(a0.w);
        u[4] = (short)f2bf(a1.x); u[5] = (short)f2bf(a1.y);
        u[6] = (short)f2bf(a1.z); u[7] = (short)f2bf(a1.w);
        af[kc] = u;
    }

    const float* W0 = isQ ? Wq : Wkv;
#pragma unroll
    for (int it = 0; it < 8; ++it) {
        int flat = it * 256 + tid;
        int c = flat >> 4, ck = flat & 15;
        int slot = (c & 7) * 16 + (c >> 3);
        const float4* s = (const float4*)&W0[(size_t)c * DIM + ck * 8];
        float4 f0 = s[0], f1 = s[1];
        short8 u;
        u[0] = (short)f2bf(f0.x); u[1] = (short)f2bf(f0.y);
        u[2] = (short)f2bf(f0.z); u[3] = (short)f2bf(f0.w);
        u[4] = (short)f2bf(f1.x); u[5] = (short)f2bf(f1.y);
        u[6] = (short)f2bf(f1.z); u[7] = (short)f2bf(f1.w);
        *(short8*)&wl[slot * LDB + ck * 8] = u;
    }
    __syncthreads();

    f32x4 acck[8];
#pragma unroll
    for (int j = 0; j < 8; ++j) acck[j] = (f32x4){0.f, 0.f, 0.f, 0.f};
#pragma unroll
    for (int kc = 0; kc < 4; ++kc)
#pragma unroll
        for (int j = 0; j < 8; ++j) {
            short8 bf = *(const short8*)&wl[(j * 16 + lrow) * LDB + kc * 32 + kg * 8];
            acck[j] = __builtin_amdgcn_mfma_f32_16x16x32_bf16(af[kc], bf, acck[j], 0, 0, 0);
        }

    f32x4 accv[8];
    if (!isQ) {
        __syncthreads();
#pragma unroll
        for (int it = 0; it < 8; ++it) {
            int flat = it * 256 + tid;
            int c = flat >> 4, ck = flat & 15;
            int slot = (c & 7) * 16 + (c >> 3);
            const float4* s = (const float4*)&Wkv[(size_t)(128 + c) * DIM + ck * 8];
            float4 f0 = s[0], f1 = s[1];
            short8 u;
            u[0] = (short)f2bf(f0.x); u[1] = (short)f2bf(f0.y);
            u[2] = (short)f2bf(f0.z); u[3] = (short)f2bf(f0.w);
            u[4] = (short)f2bf(f1.x); u[5] = (short)f2bf(f1.y);
            u[6] = (short)f2bf(f1.z); u[7] = (short)f2bf(f1.w);
            *(short8*)&wl[slot * LDB + ck * 8] = u;
        }
        __syncthreads();
#pragma unroll
        for (int j = 0; j < 8; ++j) accv[j] = (f32x4){0.f, 0.f, 0.f, 0.f};
#pragma unroll
        for (int kc = 0; kc < 4; ++kc)
#pragma unroll
            for (int j = 0; j < 8; ++j) {
                short8 bf = *(const short8*)&wl[(j * 16 + lrow) * LDB + kc * 32 + kg * 8];
                accv[j] = __builtin_amdgcn_mfma_f32_16x16x32_bf16(af[kc], bf, accv[j], 0, 0, 0);
            }
    }

    if (isQ) {
        float bias[8];
        *(float4*)&bias[0] = *(const float4*)&bq[lrow * 8];
        *(float4*)&bias[4] = *(const float4*)&bq[lrow * 8 + 4];
#pragma unroll
        for (int r = 0; r < 4; ++r) {
            int gr = rbase + kg * 4 + r;
            if (gr < n) {
                uint2 qd;
                PACK8(acck[0][r] + bias[0], acck[1][r] + bias[1], acck[2][r] + bias[2],
                      acck[3][r] + bias[3], acck[4][r] + bias[4], acck[5][r] + bias[5],
                      acck[6][r] + bias[6], acck[7][r] + bias[7], qd);
                *(uint2*)&qo[(size_t)gr * 128 + lrow * 8] = qd;
            }
        }
    } else {
        float bk_[8], bv_[8];
        *(float4*)&bk_[0] = *(const float4*)&bkv[lrow * 8];
        *(float4*)&bk_[4] = *(const float4*)&bkv[lrow * 8 + 4];
        *(float4*)&bv_[0] = *(const float4*)&bkv[128 + lrow * 8];
        *(float4*)&bv_[4] = *(const float4*)&bkv[128 + lrow * 8 + 4];
#pragma unroll
        for (int r = 0; r < 4; ++r) {
            int gr = rbase + kg * 4 + r;
            if (gr < n) {
                uint2 kd;
                PACK8(acck[0][r] + bk_[0], acck[1][r] + bk_[1], acck[2][r] + bk_[2],
                      acck[3][r] + bk_[3], acck[4][r] + bk_[4], acck[5][r] + bk_[5],
                      acck[6][r] + bk_[6], acck[7][r] + bk_[7], kd);
                u16 o[8];
#pragma unroll
                for (int j = 0; j < 8; ++j) o[j] = f2h(accv[j][r] + bv_[j]);   // f16 v
                uint4 vd;
                vd.x = (u32)o[0] | ((u32)o[1] << 16);
                vd.y = (u32)o[2] | ((u32)o[3] << 16);
                vd.z = (u32)o[4] | ((u32)o[5] << 16);
                vd.w = (u32)o[6] | ((u32)o[7] << 16);
                u8* rec = kvo + (size_t)gr * KVREC;
                *(uint2*)(rec + lrow * 8) = kd;
                *(uint4*)(rec + 128 + lrow * 16) = vd;
            }
        }
    }
}

// ---- MFMA bf16 GEMM, bf16 X input, fp32 out (final projection) ----
__global__ __launch_bounds__(256, 4)
void gemm_mfma_b(const u16* __restrict__ X, const float* __restrict__ W,
                 const float* __restrict__ b, float* __restrict__ Y, int n) {
    __shared__ __align__(16) u16 wl[DIM * LDB];
    const int tid = threadIdx.x;
#pragma unroll
    for (int it = 0; it < 8; ++it) {
        int c8 = it * 256 + tid;
        int row = c8 >> 4, ck = c8 & 15;
        const float4* s = (const float4*)&W[(size_t)row * DIM + ck * 8];
        float4 f0 = s[0], f1 = s[1];
        short8 u;
        u[0] = (short)f2bf(f0.x); u[1] = (short)f2bf(f0.y);
        u[2] = (short)f2bf(f0.z); u[3] = (short)f2bf(f0.w);
        u[4] = (short)f2bf(f1.x); u[5] = (short)f2bf(f1.y);
        u[6] = (short)f2bf(f1.z); u[7] = (short)f2bf(f1.w);
        *(short8*)&wl[row * LDB + ck * 8] = u;
    }
    __syncthreads();
    const int lane = tid & 63, wave = tid >> 6;
    const int lrow = lane & 15, kg = lane >> 4;
    const int rbase = blockIdx.x * BM + wave * 16;
    int xr = rbase + lrow; if (xr > n - 1) xr = n - 1;
    const u16* xp = X + (size_t)xr * DIM + kg * 8;

    f32x4 acc[8];
#pragma unroll
    for (int j = 0; j < 8; ++j) acc[j] = (f32x4){0.f, 0.f, 0.f, 0.f};

#pragma unroll
    for (int kc = 0; kc < 4; ++kc) {
        short8 af = *(const short8*)(xp + kc * 32);
#pragma unroll
        for (int j = 0; j < 8; ++j) {
            short8 bf = *(const short8*)&wl[(j * 16 + lrow) * LDB + kc * 32 + kg * 8];
            acc[j] = __builtin_amdgcn_mfma_f32_16x16x32_bf16(af, bf, acc[j], 0, 0, 0);
        }
    }
#pragma unroll
    for (int r = 0; r < 4; ++r) {
        int gr = rbase + kg * 4 + r;
        if (gr < n) {
#pragma unroll
            for (int j = 0; j < 8; ++j) {
                int c = j * 16 + lrow;
                Y[(size_t)gr * DIM + c] = acc[j][r] + b[c];
            }
        }
    }
}

// ONE WAVE per dst, 4 dst per block. Thread = (edge slot g=lane>>3, head
// h=lane&7). q fp8 (16B/head), 384B kv records: k fp8 (16B/head-lane),
// v f16 consumed PACKED via v_pk_fma_f16 (no per-edge unpack; acc = 8 half2
// regs, fewer live values than the bf16 path). Unpack to f32 once per dst
// before the cross-lane reduce.
__global__ __launch_bounds__(256, 8)
void edge_attn12(const u8* __restrict__ q, const u8* __restrict__ kv,
                 const int* __restrict__ sidx, const int* __restrict__ seg,
                 u16* __restrict__ hout, int n_dst) {
    const int wave = threadIdx.x >> 6;
    const int lane = threadIdx.x & 63;
    const int dst = blockIdx.x * 4 + wave;
    if (dst >= n_dst) return;
    const int g = lane >> 3, h = lane & 7;

    const int s0 = seg[dst], s1 = seg[dst + 1];

    uint4 qa = *(const uint4*)(q + (size_t)dst * 128 + h * 16);
    float qf[16];
    DEC4(qa.x, qf[0],  qf[1],  qf[2],  qf[3]);
    DEC4(qa.y, qf[4],  qf[5],  qf[6],  qf[7]);
    DEC4(qa.z, qf[8],  qf[9],  qf[10], qf[11]);
    DEC4(qa.w, qf[12], qf[13], qf[14], qf[15]);

    float ssum = 0.f;
    __half2 acc[8];
#pragma unroll
    for (int j = 0; j < 8; ++j) acc[j] = __float2half2_rn(0.f);

#pragma unroll 2
    for (int e = s0 + g; e < s1; e += 8) {
        const int row = sidx[e];
        const u8* rec = kv + (size_t)row * KVREC;
        uint4 k4 = *(const uint4*)(rec + h * 16);
        uint4 v0 = *(const uint4*)(rec + 128 + h * 32);
        uint4 v1 = *(const uint4*)(rec + 128 + h * 32 + 16);
        float d = 0.f;
        DEC_FMA(k4.x, qf[0],  qf[1],  qf[2],  qf[3],  d);
        DEC_FMA(k4.y, qf[4],  qf[5],  qf[6],  qf[7],  d);
        DEC_FMA(k4.z, qf[8],  qf[9],  qf[10], qf[11], d);
        DEC_FMA(k4.w, qf[12], qf[13], qf[14], qf[15], d);
        float lg = d * 0.25f;
        lg = (lg >= 0.f) ? lg : 0.2f * lg;
        const float p = __expf(lg);
        ssum += p;
        const __half2 p2 = __float2half2_rn(p);
        HACC(v0.x, p2, acc[0]);
        HACC(v0.y, p2, acc[1]);
        HACC(v0.z, p2, acc[2]);
        HACC(v0.w, p2, acc[3]);
        HACC(v1.x, p2, acc[4]);
        HACC(v1.y, p2, acc[5]);
        HACC(v1.z, p2, acc[6]);
        HACC(v1.w, p2, acc[7]);
    }

    // unpack once per dst, then f32 cross-slot reduce (precision preserved)
    float accf[16];
#pragma unroll
    for (int j = 0; j < 8; ++j) {
        float2 f = __half22float2(acc[j]);
        accf[2 * j] = f.x; accf[2 * j + 1] = f.y;
    }
#pragma unroll
    for (int j = 0; j < 16; ++j) {
        accf[j] += __shfl_xor(accf[j], 8);
        accf[j] += __shfl_xor(accf[j], 16);
        accf[j] += __shfl_xor(accf[j], 32);
    }
    ssum += __shfl_xor(ssum, 8);
    ssum += __shfl_xor(ssum, 16);
    ssum += __shfl_xor(ssum, 32);

    if (g == 0) {
        const float inv = (ssum > 0.f) ? 1.f / ssum : 0.f;
        u16 o[16];
#pragma unroll
        for (int j = 0; j < 16; ++j) o[j] = f2bf(accf[j] * inv);
        uint4 pa, pb;
        pa.x = (u32)o[0]  | ((u32)o[1]  << 16);
        pa.y = (u32)o[2]  | ((u32)o[3]  << 16);
        pa.z = (u32)o[4]  | ((u32)o[5]  << 16);
        pa.w = (u32)o[6]  | ((u32)o[7]  << 16);
        pb.x = (u32)o[8]  | ((u32)o[9]  << 16);
        pb.y = (u32)o[10] | ((u32)o[11] << 16);
        pb.z = (u32)o[12] | ((u32)o[13] << 16);
        pb.w = (u32)o[14] | ((u32)o[15] << 16);
        ((uint4*)hout)[(size_t)dst * 16 + h * 2]     = pa;
        ((uint4*)hout)[(size_t)dst * 16 + h * 2 + 1] = pb;
    }
}

extern "C" void kernel_launch(void* const* d_in, const int* in_sizes, int n_in,
                              void* d_out, int out_size, void* d_ws, size_t ws_size,
                              hipStream_t stream) {
    const float* feat_src = (const float*)d_in[0];
    const float* feat_dst = (const float*)d_in[1];
    const int*   src_idx  = (const int*)d_in[2];
    const int*   dst_idx  = (const int*)d_in[3];
    const float* Wq = (const float*)d_in[4];
    const float* bq = (const float*)d_in[5];
    const float* Wk = (const float*)d_in[6];
    const float* bk = (const float*)d_in[7];
    const float* Wv = (const float*)d_in[8];
    const float* bv = (const float*)d_in[9];
    const float* R  = (const float*)d_in[10];
    const float* Wo = (const float*)d_in[11];
    const float* bo = (const float*)d_in[12];

    const int n_src = in_sizes[0] / DIM;
    const int n_dst = in_sizes[1] / DIM;
    const int E     = in_sizes[2];

    float* out = (float*)d_out;
    u8*  q   = (u8*)d_ws;                               // n_dst x 128 fp8
    u8*  kv  = q + (size_t)n_dst * 128;                 // n_src x 384B (k fp8 | v f16)
    u16* hag = (u16*)(kv + (size_t)n_src * KVREC);      // n_dst x 128 bf16
    int* seg = (int*)(hag + (size_t)n_dst * DIM);       // n_dst+1 ints
    size_t segEnd = ((size_t)(n_dst + 1) + 3) & ~(size_t)3;
    float* Wkv = (float*)(seg + segEnd);                // 256x128 fp32
    float* bkv = Wkv + 256 * DIM;                       // 256 fp32

    const int gq = (n_dst + BM - 1) / BM;
    const int gs = (n_src + BM - 1) / BM;
    const int gE = (E + 255) / 256;

    fold_relation_kv<<<256, DIM, 0, stream>>>(Wk, bk, Wv, bv, R, Wkv, bkv);
    proj_all<<<gq + gs + gE, 256, 0, stream>>>(feat_src, feat_dst, Wq, bq, Wkv, bkv,
                                               dst_idx, seg, E, q, kv, n_dst, n_src, gq, gs);
    edge_attn12<<<(n_dst + 3) / 4, 256, 0, stream>>>(q, kv, src_idx, seg, hag, n_dst);
    gemm_mfma_b<<<gq, 256, 0, stream>>>(hag, Wo, bo, out, n_dst);
}